// Round 3
// baseline (1827.362 us; speedup 1.0000x reference)
//
#include <hip/hip_runtime.h>

// ---------------- zero-fill helpers (graph-capture-safe; no hipMemsetAsync) ----

__global__ void zero_i32_kernel(int* __restrict__ p, int n) {
    int i = blockIdx.x * 256 + threadIdx.x;
    if (i < n) p[i] = 0;
}

__global__ void zero_bn_kernel(float* __restrict__ bnbuf) {
    int t = threadIdx.x;
    if (t < 128) bnbuf[t] = 0.f;
}

__global__ void zero_pool_kernel(float* __restrict__ pooled, float* __restrict__ gd,
                                 unsigned* __restrict__ gm) {
    int t = blockIdx.x * 256 + threadIdx.x;
    if (t < 4096) pooled[t] = 0.f;
    if (t < 64) { gd[t] = 0.f; gm[t] = 0u; }
}

// ---------------- encoders & weight prep ----------------

// h[n][c] = sum_j x[n][j]*node_W[j][c] + node_b[c]
__global__ void node_enc_kernel(const float* __restrict__ x, const float* __restrict__ node_W,
                                const float* __restrict__ node_b, float* __restrict__ h, int N) {
    int idx = blockIdx.x * 256 + threadIdx.x;
    if (idx >= N * 64) return;
    int n = idx >> 6, c = idx & 63;
    float acc = node_b[c];
#pragma unroll
    for (int j = 0; j < 16; ++j) acc += x[n * 16 + j] * node_W[j * 64 + c];
    h[idx] = acc;
}

// Wc[l][d][j] = sum_m edge_W[d][m]*We[l][m][j];  bcb[l][j] = sum_m edge_b[m]*We[l][m][j] + be[l][j]
__global__ void combine_w_kernel(const float* __restrict__ edge_W, const float* __restrict__ edge_b,
                                 const float* __restrict__ We, const float* __restrict__ be,
                                 float* __restrict__ Wc, float* __restrict__ bcb) {
    int tid = blockIdx.x * 256 + threadIdx.x;
    if (tid < 2048) {
        int l = tid >> 10, d = (tid >> 7) & 7, j = tid & 127;
        float s = 0.f;
        for (int m = 0; m < 64; ++m) s += edge_W[d * 64 + m] * We[l * 8192 + m * 128 + j];
        Wc[l * 1024 + d * 128 + j] = s;
    } else if (tid < 2048 + 256) {
        int u = tid - 2048;
        int l = u >> 7, j = u & 127;
        float s = be[l * 128 + j];
        for (int m = 0; m < 64; ++m) s += edge_b[m] * We[l * 8192 + m * 128 + j];
        bcb[l * 128 + j] = s;
    }
}

// ---------------- CSR build (by dst) ----------------

__global__ void csr_count_kernel(const int* __restrict__ dst, int* __restrict__ counts,
                                 int E, int N) {
    int e = blockIdx.x * 256 + threadIdx.x;
    if (e < E) {
        int d = dst[e];
        d = (d < 0) ? 0 : ((d >= N) ? N - 1 : d);
        atomicAdd(&counts[d], 1);
    }
}

__global__ void scan1_kernel(const int* __restrict__ counts, int* __restrict__ rowptr,
                             int* __restrict__ bsums, int N) {
    __shared__ int s[256];
    int t = threadIdx.x, i = blockIdx.x * 256 + t;
    int v = (i < N) ? counts[i] : 0;
    s[t] = v;
    __syncthreads();
    for (int d = 1; d < 256; d <<= 1) {
        int x = (t >= d) ? s[t - d] : 0;
        __syncthreads();
        s[t] += x;
        __syncthreads();
    }
    if (i < N) rowptr[i] = s[t] - v;  // exclusive within block
    if (t == 255) bsums[blockIdx.x] = s[255];
}

__global__ void scan2_kernel(int* __restrict__ bsums, int nb) {
    __shared__ int s[256];
    int t = threadIdx.x;
    int v = (t < nb) ? bsums[t] : 0;
    s[t] = v;
    __syncthreads();
    for (int d = 1; d < 256; d <<= 1) {
        int x = (t >= d) ? s[t - d] : 0;
        __syncthreads();
        s[t] += x;
        __syncthreads();
    }
    if (t < nb) bsums[t] = s[t] - v;  // exclusive
}

__global__ void scan3_kernel(int* __restrict__ rowptr, const int* __restrict__ bsums,
                             int* __restrict__ cursor, int N, int E) {
    int i = blockIdx.x * 256 + threadIdx.x;
    if (i < N) {
        int r = rowptr[i] + bsums[i >> 8];
        rowptr[i] = r;
        cursor[i] = r;
    }
    if (i == 0) rowptr[N] = E;
}

__global__ void csr_fill_kernel(const int* __restrict__ dst, int* __restrict__ cursor,
                                int* __restrict__ csr, int E, int N) {
    int e = blockIdx.x * 256 + threadIdx.x;
    if (e < E) {
        int d = dst[e];
        d = (d < 0) ? 0 : ((d >= N) ? N - 1 : d);
        int pos = atomicAdd(&cursor[d], 1);
        pos = (pos < 0) ? 0 : ((pos >= E) ? E - 1 : pos);
        csr[pos] = e;
    }
}

// ---------------- per-layer kernels ----------------

// qkv[n][sel*128 + t] = sum_j h[n][j]*W_sel[j][t] + b_sel[t]; grid=(ceil(N/8),3), block=128
__global__ __launch_bounds__(128) void qkv_kernel(
    const float* __restrict__ h,
    const float* __restrict__ Wq, const float* __restrict__ bq,
    const float* __restrict__ Wk, const float* __restrict__ bk,
    const float* __restrict__ Wv, const float* __restrict__ bv,
    float* __restrict__ qkv, int N) {
    int sel = blockIdx.y;
    const float* W = (sel == 0) ? Wq : ((sel == 1) ? Wk : Wv);
    const float* b = (sel == 0) ? bq : ((sel == 1) ? bk : bv);
    __shared__ float hs[8 * 64];
    int t = threadIdx.x;
    int n0 = blockIdx.x * 8;
    for (int i = t; i < 512; i += 128) {
        int n = n0 + (i >> 6);
        hs[i] = (n < N) ? h[n * 64 + (i & 63)] : 0.f;
    }
    __syncthreads();
    float acc[8] = {0.f, 0.f, 0.f, 0.f, 0.f, 0.f, 0.f, 0.f};
    for (int j = 0; j < 64; ++j) {
        float w = W[j * 128 + t];
#pragma unroll
        for (int g = 0; g < 8; ++g) acc[g] += hs[g * 64 + j] * w;
    }
    float bias = b[t];
#pragma unroll
    for (int g = 0; g < 8; ++g) {
        int n = n0 + g;
        if (n < N) qkv[(size_t)n * 384 + sel * 128 + t] = acc[g] + bias;
    }
}

// one wave per dst node: online-softmax attention over in-edges + skip matmul
__global__ __launch_bounds__(256) void attn_kernel(
    const float* __restrict__ h, const float* __restrict__ qkv,
    const float* __restrict__ edge_attr, const int* __restrict__ edge_src,
    const int* __restrict__ rowptr, const int* __restrict__ csr,
    const float* __restrict__ Wc, const float* __restrict__ bcb,
    const float* __restrict__ Wskip, const float* __restrict__ bskip,
    float* __restrict__ outbuf, int N, int E) {
    __shared__ float Ws_s[64 * 64];
    __shared__ float Wc_s[1024];
    __shared__ float bc_s[128];
    __shared__ float bsk_s[64];
    int t = threadIdx.x;
    for (int i = t; i < 4096; i += 256) Ws_s[i] = Wskip[i];
    for (int i = t; i < 1024; i += 256) Wc_s[i] = Wc[i];
    if (t < 128) bc_s[t] = bcb[t];
    if (t < 64) bsk_s[t] = bskip[t];
    __syncthreads();
    int lane = t & 63, wid = t >> 6;
    for (int n = blockIdx.x * 4 + wid; n < N; n += gridDim.x * 4) {
        float hv = h[n * 64 + lane];
        const float* qp = qkv + (size_t)n * 384;
        float q0 = qp[lane], q1 = qp[64 + lane];
        // skip = h[n] @ Wskip + bskip
        float skip = bsk_s[lane];
        for (int j = 0; j < 64; ++j) skip += __shfl(hv, j) * Ws_s[j * 64 + lane];
        int start = rowptr[n], end = rowptr[n + 1];
        start = (start < 0) ? 0 : ((start > E) ? E : start);
        end = (end < start) ? start : ((end > E) ? E : end);
        float m0 = -1e30f, m1 = -1e30f, l0 = 0.f, l1 = 0.f, a0 = 0.f, a1 = 0.f;
        for (int i = start; i < end; ++i) {
            int e = csr[i];
            e = (e < 0) ? 0 : ((e >= E) ? E - 1 : e);
            int src = edge_src[e];
            src = (src < 0) ? 0 : ((src >= N) ? N - 1 : src);
            float ep0 = bc_s[lane], ep1 = bc_s[64 + lane];
            const float* ea = edge_attr + (size_t)e * 8;
#pragma unroll
            for (int d = 0; d < 8; ++d) {
                float av = ea[d];
                ep0 += av * Wc_s[d * 128 + lane];
                ep1 += av * Wc_s[d * 128 + 64 + lane];
            }
            const float* kp = qkv + (size_t)src * 384;
            float ke0 = kp[128 + lane] + ep0, ke1 = kp[192 + lane] + ep1;
            float ve0 = kp[256 + lane] + ep0, ve1 = kp[320 + lane] + ep1;
            float s0 = q0 * ke0, s1 = q1 * ke1;
#pragma unroll
            for (int off = 32; off; off >>= 1) {
                s0 += __shfl_xor(s0, off);
                s1 += __shfl_xor(s1, off);
            }
            s0 *= 0.125f;
            s1 *= 0.125f;
            float mn0 = fmaxf(m0, s0);
            float c0 = __expf(m0 - mn0), p0 = __expf(s0 - mn0);
            a0 = a0 * c0 + p0 * ve0;
            l0 = l0 * c0 + p0;
            m0 = mn0;
            float mn1 = fmaxf(m1, s1);
            float c1 = __expf(m1 - mn1), p1 = __expf(s1 - mn1);
            a1 = a1 * c1 + p1 * ve1;
            l1 = l1 * c1 + p1;
            m1 = mn1;
        }
        float attn = (end > start) ? 0.5f * (a0 / l0 + a1 / l1) : 0.f;
        outbuf[n * 64 + lane] = skip + attn;
    }
}

__global__ __launch_bounds__(256) void bnstats_kernel(const float* __restrict__ outbuf,
                                                      float* __restrict__ bnbuf, int N) {
    __shared__ float ssum[64], ssq[64];
    int t = threadIdx.x;
    if (t < 64) { ssum[t] = 0.f; ssq[t] = 0.f; }
    __syncthreads();
    int stride = gridDim.x * 256;  // multiple of 64
    float a = 0.f, b = 0.f;
    int idx0 = blockIdx.x * 256 + t;
    for (int idx = idx0; idx < N * 64; idx += stride) {
        float v = outbuf[idx];
        a += v;
        b += v * v;
    }
    int c = t & 63;
    atomicAdd(&ssum[c], a);
    atomicAdd(&ssq[c], b);
    __syncthreads();
    if (t < 64) {
        atomicAdd(&bnbuf[t], ssum[t]);
        atomicAdd(&bnbuf[64 + t], ssq[t]);
    }
}

__global__ void bnfinal_kernel(float* __restrict__ bnbuf, const float* __restrict__ gamma,
                               const float* __restrict__ beta, int N) {
    int c = threadIdx.x;
    if (c >= 64) return;
    float invN = 1.f / (float)N;
    float mean = bnbuf[c] * invN;
    float var = bnbuf[64 + c] * invN - mean * mean;
    float inv = rsqrtf(var + 1e-5f);
    float scale = gamma[c] * inv;
    bnbuf[128 + c] = scale;
    bnbuf[192 + c] = beta[c] - mean * scale;
}

__global__ void bnapply_kernel(const float* __restrict__ outbuf, const float* __restrict__ bnbuf,
                               float* __restrict__ h, int N) {
    int idx = blockIdx.x * 256 + threadIdx.x;
    if (idx >= N * 64) return;
    int c = idx & 63;
    float o = outbuf[idx] * bnbuf[128 + c] + bnbuf[192 + c];
    o = (o > 0.f) ? o : 0.01f * o;
    h[idx] += o;  // residual: h_new = leaky(bn(out)) + identity
}

// ---------------- pooling ----------------

__device__ __forceinline__ unsigned enc_f(float f) {
    unsigned b = __float_as_uint(f);
    return (b & 0x80000000u) ? ~b : (b | 0x80000000u);
}
__device__ __forceinline__ float dec_f(unsigned b) {
    return (b & 0x80000000u) ? __uint_as_float(b & 0x7FFFFFFFu) : __uint_as_float(~b);
}

__global__ __launch_bounds__(256) void gate_kernel(const float* __restrict__ h,
                                                   const int* __restrict__ batch,
                                                   const float* __restrict__ gate_W,
                                                   const float* __restrict__ gate_b,
                                                   float* __restrict__ gate,
                                                   unsigned* __restrict__ gm, int N) {
    int lane = threadIdx.x & 63, wid = threadIdx.x >> 6;
    int n = blockIdx.x * 4 + wid;
    if (n >= N) return;
    float g = h[n * 64 + lane] * gate_W[lane];
#pragma unroll
    for (int off = 32; off; off >>= 1) g += __shfl_xor(g, off);
    g += gate_b[0];
    if (lane == 0) {
        gate[n] = g;
        int b = batch[n];
        b = (b < 0) ? 0 : ((b >= 64) ? 63 : b);
        atomicMax(&gm[b], enc_f(g));
    }
}

__global__ __launch_bounds__(256) void pool_kernel(const float* __restrict__ h,
                                                   const int* __restrict__ batch,
                                                   const float* __restrict__ gate,
                                                   const unsigned* __restrict__ gm,
                                                   float* __restrict__ gd,
                                                   float* __restrict__ pooled, int N) {
    int lane = threadIdx.x & 63, wid = threadIdx.x >> 6;
    int n = blockIdx.x * 4 + wid;
    if (n >= N) return;
    int b = batch[n];
    b = (b < 0) ? 0 : ((b >= 64) ? 63 : b);
    float m = dec_f(gm[b]);
    float ge = __expf(gate[n] - m);
    atomicAdd(&pooled[b * 64 + lane], ge * h[n * 64 + lane]);
    if (lane == 0) atomicAdd(&gd[b], ge);
}

__global__ void final_kernel(const float* __restrict__ pooled, const float* __restrict__ gd,
                             const float* __restrict__ out_W, const float* __restrict__ out_b,
                             float* __restrict__ out, int B) {
    int b = threadIdx.x;
    if (b >= B) return;
    float inv = 1.f / gd[b];
    float s = 0.f;
    for (int c = 0; c < 64; ++c) s += pooled[b * 64 + c] * out_W[c];
    s = s * inv + out_b[0];
    out[b] = 1.f / (1.f + __expf(-s));
}

// ---------------- host ----------------

extern "C" void kernel_launch(void* const* d_in, const int* in_sizes, int n_in,
                              void* d_out, int out_size, void* d_ws, size_t ws_size,
                              hipStream_t stream) {
    const float* x         = (const float*)d_in[0];
    const float* edge_attr = (const float*)d_in[1];
    const int*   edge_src  = (const int*)d_in[2];
    const int*   edge_dst  = (const int*)d_in[3];
    const int*   batch     = (const int*)d_in[4];
    const float* node_W    = (const float*)d_in[5];
    const float* node_b    = (const float*)d_in[6];
    const float* edge_W    = (const float*)d_in[7];
    const float* edge_b    = (const float*)d_in[8];
    const float* Wq        = (const float*)d_in[9];
    const float* bq        = (const float*)d_in[10];
    const float* Wk        = (const float*)d_in[11];
    const float* bk        = (const float*)d_in[12];
    const float* Wv        = (const float*)d_in[13];
    const float* bv        = (const float*)d_in[14];
    const float* We        = (const float*)d_in[15];
    const float* be        = (const float*)d_in[16];
    const float* Wskip     = (const float*)d_in[17];
    const float* bskip     = (const float*)d_in[18];
    const float* gamma     = (const float*)d_in[19];
    const float* beta      = (const float*)d_in[20];
    const float* gate_W    = (const float*)d_in[21];
    const float* gate_b    = (const float*)d_in[22];
    const float* out_W     = (const float*)d_in[23];
    const float* out_b     = (const float*)d_in[24];
    float* out = (float*)d_out;

    const int N = in_sizes[0] / 16;
    const int E = in_sizes[2];
    const int B = out_size;

    char* ws = (char*)d_ws;
    size_t off = 0;
    auto alloc = [&](size_t bytes) {
        size_t o = off;
        off += (bytes + 255) & ~(size_t)255;
        return o;
    };
    float*    h      = (float*)(ws + alloc((size_t)N * 64 * 4));
    float*    qkv    = (float*)(ws + alloc((size_t)N * 384 * 4));
    float*    outbuf = (float*)(ws + alloc((size_t)N * 64 * 4));
    int*      rowptr = (int*)(ws + alloc((size_t)(N + 1) * 4));
    int*      cursor = (int*)(ws + alloc((size_t)N * 4));
    int*      counts = (int*)(ws + alloc((size_t)N * 4));
    int*      bsums  = (int*)(ws + alloc(1024));
    int*      csr    = (int*)(ws + alloc((size_t)E * 4));
    float*    Wc     = (float*)(ws + alloc(2 * 1024 * 4));
    float*    bcb    = (float*)(ws + alloc(2 * 128 * 4));
    float*    bnbuf  = (float*)(ws + alloc(256 * 4));
    float*    gate   = (float*)(ws + alloc((size_t)N * 4));
    unsigned* gm     = (unsigned*)(ws + alloc(64 * 4));
    float*    gd     = (float*)(ws + alloc(64 * 4));
    float*    pooled = (float*)(ws + alloc(64 * 64 * 4));
    if (off > ws_size) return;  // fail visibly (output stays zeroed)

    // encoders, combined edge weights, CSR build
    zero_i32_kernel<<<(N + 255) / 256, 256, 0, stream>>>(counts, N);
    node_enc_kernel<<<(N * 64 + 255) / 256, 256, 0, stream>>>(x, node_W, node_b, h, N);
    combine_w_kernel<<<9, 256, 0, stream>>>(edge_W, edge_b, We, be, Wc, bcb);
    csr_count_kernel<<<(E + 255) / 256, 256, 0, stream>>>(edge_dst, counts, E, N);
    int nb = (N + 255) / 256;
    scan1_kernel<<<nb, 256, 0, stream>>>(counts, rowptr, bsums, N);
    scan2_kernel<<<1, 256, 0, stream>>>(bsums, nb);
    scan3_kernel<<<nb, 256, 0, stream>>>(rowptr, bsums, cursor, N, E);
    csr_fill_kernel<<<(E + 255) / 256, 256, 0, stream>>>(edge_dst, cursor, csr, E, N);

    for (int l = 0; l < 2; ++l) {
        qkv_kernel<<<dim3((N + 7) / 8, 3), 128, 0, stream>>>(
            h, Wq + l * 8192, bq + l * 128, Wk + l * 8192, bk + l * 128,
            Wv + l * 8192, bv + l * 128, qkv, N);
        attn_kernel<<<2048, 256, 0, stream>>>(h, qkv, edge_attr, edge_src, rowptr, csr,
                                              Wc + l * 1024, bcb + l * 128,
                                              Wskip + l * 4096, bskip + l * 64, outbuf, N, E);
        zero_bn_kernel<<<1, 128, 0, stream>>>(bnbuf);
        bnstats_kernel<<<256, 256, 0, stream>>>(outbuf, bnbuf, N);
        bnfinal_kernel<<<1, 64, 0, stream>>>(bnbuf, gamma + l * 64, beta + l * 64, N);
        bnapply_kernel<<<(N * 64 + 255) / 256, 256, 0, stream>>>(outbuf, bnbuf, h, N);
    }

    zero_pool_kernel<<<16, 256, 0, stream>>>(pooled, gd, gm);
    gate_kernel<<<(N + 3) / 4, 256, 0, stream>>>(h, batch, gate_W, gate_b, gate, gm, N);
    pool_kernel<<<(N + 3) / 4, 256, 0, stream>>>(h, batch, gate, gm, gd, pooled, N);
    final_kernel<<<1, 64, 0, stream>>>(pooled, gd, out_W, out_b, out, B);
}

// Round 4
// 858.229 us; speedup vs baseline: 2.1292x; 2.1292x over previous
//
#include <hip/hip_runtime.h>

// ---------------- zero-fill helpers (graph-capture-safe; no hipMemsetAsync) ----

__global__ void zero_i32_kernel(int* __restrict__ p, int n) {
    int i = blockIdx.x * 256 + threadIdx.x;
    if (i < n) p[i] = 0;
}

__global__ void zero_bn_kernel(float* __restrict__ bnbuf) {
    int t = threadIdx.x;
    if (t < 128) bnbuf[t] = 0.f;
}

// ---------------- encoders & weight prep ----------------

__global__ void node_enc_kernel(const float* __restrict__ x, const float* __restrict__ node_W,
                                const float* __restrict__ node_b, float* __restrict__ h, int N) {
    int idx = blockIdx.x * 256 + threadIdx.x;
    if (idx >= N * 64) return;
    int n = idx >> 6, c = idx & 63;
    float acc = node_b[c];
#pragma unroll
    for (int j = 0; j < 16; ++j) acc += x[n * 16 + j] * node_W[j * 64 + c];
    h[idx] = acc;
}

// Wc[l][d][j] = sum_m edge_W[d][m]*We[l][m][j];  bcb[l][j] = sum_m edge_b[m]*We[l][m][j] + be[l][j]
__global__ void combine_w_kernel(const float* __restrict__ edge_W, const float* __restrict__ edge_b,
                                 const float* __restrict__ We, const float* __restrict__ be,
                                 float* __restrict__ Wc, float* __restrict__ bcb) {
    int tid = blockIdx.x * 256 + threadIdx.x;
    if (tid < 2048) {
        int l = tid >> 10, d = (tid >> 7) & 7, j = tid & 127;
        float s = 0.f;
        for (int m = 0; m < 64; ++m) s += edge_W[d * 64 + m] * We[l * 8192 + m * 128 + j];
        Wc[l * 1024 + d * 128 + j] = s;
    } else if (tid < 2048 + 256) {
        int u = tid - 2048;
        int l = u >> 7, j = u & 127;
        float s = be[l * 128 + j];
        for (int m = 0; m < 64; ++m) s += edge_b[m] * We[l * 8192 + m * 128 + j];
        bcb[l * 128 + j] = s;
    }
}

// ---------------- CSR build (by dst) ----------------

__global__ void csr_count_kernel(const int* __restrict__ dst, int* __restrict__ counts, int E) {
    int e = blockIdx.x * 256 + threadIdx.x;
    if (e < E) atomicAdd(&counts[dst[e]], 1);
}

__global__ void scan1_kernel(const int* __restrict__ counts, int* __restrict__ rowptr,
                             int* __restrict__ bsums, int N) {
    __shared__ int s[256];
    int t = threadIdx.x, i = blockIdx.x * 256 + t;
    int v = (i < N) ? counts[i] : 0;
    s[t] = v;
    __syncthreads();
    for (int d = 1; d < 256; d <<= 1) {
        int x = (t >= d) ? s[t - d] : 0;
        __syncthreads();
        s[t] += x;
        __syncthreads();
    }
    if (i < N) rowptr[i] = s[t] - v;
    if (t == 255) bsums[blockIdx.x] = s[255];
}

__global__ void scan2_kernel(int* __restrict__ bsums, int nb) {
    __shared__ int s[256];
    int t = threadIdx.x;
    int v = (t < nb) ? bsums[t] : 0;
    s[t] = v;
    __syncthreads();
    for (int d = 1; d < 256; d <<= 1) {
        int x = (t >= d) ? s[t - d] : 0;
        __syncthreads();
        s[t] += x;
        __syncthreads();
    }
    if (t < nb) bsums[t] = s[t] - v;
}

__global__ void scan3_kernel(int* __restrict__ rowptr, const int* __restrict__ bsums,
                             int* __restrict__ cursor, int N, int E) {
    int i = blockIdx.x * 256 + threadIdx.x;
    if (i < N) {
        int r = rowptr[i] + bsums[i >> 8];
        rowptr[i] = r;
        cursor[i] = r;
    }
    if (i == 0) rowptr[N] = E;
}

__global__ void csr_fill_kernel(const int* __restrict__ dst, int* __restrict__ cursor,
                                int* __restrict__ csr, int E) {
    int e = blockIdx.x * 256 + threadIdx.x;
    if (e < E) {
        int pos = atomicAdd(&cursor[dst[e]], 1);
        csr[pos] = e;
    }
}

// ---------------- per-layer kernels ----------------

// sel 0..2: qkv[n][sel*128+t] = h[n]·Wsel[:,t] + bsel[t]   (128 cols)
// sel 3:    outbuf[n][t]      = h[n]·Wskip[:,t] + bskip[t] (64 cols; attn adds onto it)
__global__ __launch_bounds__(128) void qkv_kernel(
    const float* __restrict__ h,
    const float* __restrict__ Wq, const float* __restrict__ bq,
    const float* __restrict__ Wk, const float* __restrict__ bk,
    const float* __restrict__ Wv, const float* __restrict__ bv,
    const float* __restrict__ Wskip, const float* __restrict__ bskip,
    float* __restrict__ qkv, float* __restrict__ outbuf, int N) {
    int sel = blockIdx.y;
    const float* W = (sel == 0) ? Wq : ((sel == 1) ? Wk : ((sel == 2) ? Wv : Wskip));
    const float* b = (sel == 0) ? bq : ((sel == 1) ? bk : ((sel == 2) ? bv : bskip));
    int cols = (sel == 3) ? 64 : 128;
    __shared__ float hs[8 * 64];
    int t = threadIdx.x;
    int n0 = blockIdx.x * 8;
    for (int i = t; i < 512; i += 128) {
        int n = n0 + (i >> 6);
        hs[i] = (n < N) ? h[n * 64 + (i & 63)] : 0.f;
    }
    __syncthreads();
    if (t >= cols) return;
    float acc[8] = {0.f, 0.f, 0.f, 0.f, 0.f, 0.f, 0.f, 0.f};
    for (int j = 0; j < 64; ++j) {
        float w = W[j * cols + t];
#pragma unroll
        for (int g = 0; g < 8; ++g) acc[g] += hs[g * 64 + j] * w;
    }
    float bias = b[t];
#pragma unroll
    for (int g = 0; g < 8; ++g) {
        int n = n0 + g;
        if (n < N) {
            if (sel == 3) outbuf[(size_t)n * 64 + t] = acc[g] + bias;
            else          qkv[(size_t)n * 384 + sel * 128 + t] = acc[g] + bias;
        }
    }
}

// one wave per dst node: online-softmax attention over in-edges; adds onto skip in outbuf
__global__ __launch_bounds__(256) void attn_kernel(
    const float* __restrict__ qkv,
    const float* __restrict__ edge_attr, const int* __restrict__ edge_src,
    const int* __restrict__ rowptr, const int* __restrict__ csr,
    const float* __restrict__ Wc, const float* __restrict__ bcb,
    float* __restrict__ outbuf, int N) {
    __shared__ float Wc_s[1024];
    __shared__ float bc_s[128];
    int t = threadIdx.x;
    for (int i = t; i < 1024; i += 256) Wc_s[i] = Wc[i];
    if (t < 128) bc_s[t] = bcb[t];
    __syncthreads();
    int lane = t & 63, wid = t >> 6;
    for (int n = blockIdx.x * 4 + wid; n < N; n += gridDim.x * 4) {
        const float* qp = qkv + (size_t)n * 384;
        float q0 = qp[lane], q1 = qp[64 + lane];
        int start = rowptr[n], end = rowptr[n + 1];
        float m0 = -1e30f, m1 = -1e30f, l0 = 0.f, l1 = 0.f, a0 = 0.f, a1 = 0.f;
        int e = (start < end) ? csr[start] : 0;
        int src = (start < end) ? edge_src[e] : 0;
        for (int i = start; i < end; ++i) {
            int e_c = e, src_c = src;
            if (i + 1 < end) {            // prefetch next indices to shorten dep chain
                e = csr[i + 1];
                src = edge_src[e];
            }
            const float4 ea0 = *(const float4*)(edge_attr + (size_t)e_c * 8);
            const float4 ea1 = *(const float4*)(edge_attr + (size_t)e_c * 8 + 4);
            float ep0 = bc_s[lane], ep1 = bc_s[64 + lane];
            ep0 += ea0.x * Wc_s[0 * 128 + lane] + ea0.y * Wc_s[1 * 128 + lane] +
                   ea0.z * Wc_s[2 * 128 + lane] + ea0.w * Wc_s[3 * 128 + lane] +
                   ea1.x * Wc_s[4 * 128 + lane] + ea1.y * Wc_s[5 * 128 + lane] +
                   ea1.z * Wc_s[6 * 128 + lane] + ea1.w * Wc_s[7 * 128 + lane];
            ep1 += ea0.x * Wc_s[0 * 128 + 64 + lane] + ea0.y * Wc_s[1 * 128 + 64 + lane] +
                   ea0.z * Wc_s[2 * 128 + 64 + lane] + ea0.w * Wc_s[3 * 128 + 64 + lane] +
                   ea1.x * Wc_s[4 * 128 + 64 + lane] + ea1.y * Wc_s[5 * 128 + 64 + lane] +
                   ea1.z * Wc_s[6 * 128 + 64 + lane] + ea1.w * Wc_s[7 * 128 + 64 + lane];
            const float* kp = qkv + (size_t)src_c * 384;
            float ke0 = kp[128 + lane] + ep0, ke1 = kp[192 + lane] + ep1;
            float ve0 = kp[256 + lane] + ep0, ve1 = kp[320 + lane] + ep1;
            float s0 = q0 * ke0, s1 = q1 * ke1;
#pragma unroll
            for (int off = 32; off; off >>= 1) {
                s0 += __shfl_xor(s0, off);
                s1 += __shfl_xor(s1, off);
            }
            s0 *= 0.125f;
            s1 *= 0.125f;
            float mn0 = fmaxf(m0, s0);
            float c0 = __expf(m0 - mn0), p0 = __expf(s0 - mn0);
            a0 = a0 * c0 + p0 * ve0;
            l0 = l0 * c0 + p0;
            m0 = mn0;
            float mn1 = fmaxf(m1, s1);
            float c1 = __expf(m1 - mn1), p1 = __expf(s1 - mn1);
            a1 = a1 * c1 + p1 * ve1;
            l1 = l1 * c1 + p1;
            m1 = mn1;
        }
        float attn = (end > start) ? 0.5f * (a0 / l0 + a1 / l1) : 0.f;
        size_t oi = (size_t)n * 64 + lane;
        outbuf[oi] = outbuf[oi] + attn;   // outbuf holds skip from qkv_kernel sel==3
    }
}

__global__ __launch_bounds__(256) void bnstats_kernel(const float* __restrict__ outbuf,
                                                      float* __restrict__ bnbuf, int N) {
    __shared__ float ssum[64], ssq[64];
    int t = threadIdx.x;
    if (t < 64) { ssum[t] = 0.f; ssq[t] = 0.f; }
    __syncthreads();
    int stride = gridDim.x * 256;
    float a = 0.f, b = 0.f;
    int idx0 = blockIdx.x * 256 + t;
    for (int idx = idx0; idx < N * 64; idx += stride) {
        float v = outbuf[idx];
        a += v;
        b += v * v;
    }
    int c = t & 63;
    atomicAdd(&ssum[c], a);
    atomicAdd(&ssq[c], b);
    __syncthreads();
    if (t < 64) {
        atomicAdd(&bnbuf[t], ssum[t]);
        atomicAdd(&bnbuf[64 + t], ssq[t]);
    }
}

__global__ void bnfinal_kernel(float* __restrict__ bnbuf, const float* __restrict__ gamma,
                               const float* __restrict__ beta, int N) {
    int c = threadIdx.x;
    if (c >= 64) return;
    float invN = 1.f / (float)N;
    float mean = bnbuf[c] * invN;
    float var = bnbuf[64 + c] * invN - mean * mean;
    float inv = rsqrtf(var + 1e-5f);
    float scale = gamma[c] * inv;
    bnbuf[128 + c] = scale;
    bnbuf[192 + c] = beta[c] - mean * scale;
}

__global__ void bnapply_kernel(const float* __restrict__ outbuf, const float* __restrict__ bnbuf,
                               float* __restrict__ h, int N) {
    int idx = blockIdx.x * 256 + threadIdx.x;
    if (idx >= N * 64) return;
    int c = idx & 63;
    float o = outbuf[idx] * bnbuf[128 + c] + bnbuf[192 + c];
    o = (o > 0.f) ? o : 0.01f * o;
    h[idx] += o;
}

// ---------------- pooling: one block per graph (batch is sorted; no atomics) ----

__global__ __launch_bounds__(256) void pool_kernel(
    const float* __restrict__ h, const int* __restrict__ batch,
    const float* __restrict__ gate_W, const float* __restrict__ gate_b,
    float* __restrict__ gatebuf, float* __restrict__ pooled,
    float* __restrict__ gd, int N) {
    int b = blockIdx.x;
    // binary search [start,end) of batch==b in sorted batch array
    int lo = 0, hi = N;
    while (lo < hi) { int mid = (lo + hi) >> 1; if (batch[mid] < b) lo = mid + 1; else hi = mid; }
    int start = lo;
    lo = start; hi = N;
    while (lo < hi) { int mid = (lo + hi) >> 1; if (batch[mid] <= b) lo = mid + 1; else hi = mid; }
    int end = lo;
    int lane = threadIdx.x & 63, wid = threadIdx.x >> 6;
    float gw = gate_W[lane];
    float gb = gate_b[0];
    __shared__ float smax[4];
    __shared__ float sacc[4][64];
    __shared__ float sden[4];
    // phase A: gate value + per-wave max
    float wmax = -1e30f;
    for (int n = start + wid; n < end; n += 4) {
        float g = h[(size_t)n * 64 + lane] * gw;
#pragma unroll
        for (int off = 32; off; off >>= 1) g += __shfl_xor(g, off);
        g += gb;
        if (lane == 0) gatebuf[n] = g;
        wmax = fmaxf(wmax, g);
    }
    if (lane == 0) smax[wid] = wmax;
    __syncthreads();
    float m = fmaxf(fmaxf(smax[0], smax[1]), fmaxf(smax[2], smax[3]));
    // phase B: exp-weighted accumulate
    float acc = 0.f, den = 0.f;
    for (int n = start + wid; n < end; n += 4) {
        float ge = __expf(gatebuf[n] - m);
        acc += ge * h[(size_t)n * 64 + lane];
        den += ge;
    }
    sacc[wid][lane] = acc;
    if (lane == 0) sden[wid] = den;
    __syncthreads();
    if (wid == 0) {
        pooled[b * 64 + lane] = sacc[0][lane] + sacc[1][lane] + sacc[2][lane] + sacc[3][lane];
        if (lane == 0) {
            float d = sden[0] + sden[1] + sden[2] + sden[3];
            gd[b] = (end > start) ? d : 1.f;
        }
    }
}

__global__ void final_kernel(const float* __restrict__ pooled, const float* __restrict__ gd,
                             const float* __restrict__ out_W, const float* __restrict__ out_b,
                             float* __restrict__ out, int B) {
    int b = threadIdx.x;
    if (b >= B) return;
    float inv = 1.f / gd[b];
    float s = 0.f;
    for (int c = 0; c < 64; ++c) s += pooled[b * 64 + c] * out_W[c];
    s = s * inv + out_b[0];
    out[b] = 1.f / (1.f + __expf(-s));
}

// ---------------- host ----------------

extern "C" void kernel_launch(void* const* d_in, const int* in_sizes, int n_in,
                              void* d_out, int out_size, void* d_ws, size_t ws_size,
                              hipStream_t stream) {
    const float* x         = (const float*)d_in[0];
    const float* edge_attr = (const float*)d_in[1];
    const int*   edge_src  = (const int*)d_in[2];
    const int*   edge_dst  = (const int*)d_in[3];
    const int*   batch     = (const int*)d_in[4];
    const float* node_W    = (const float*)d_in[5];
    const float* node_b    = (const float*)d_in[6];
    const float* edge_W    = (const float*)d_in[7];
    const float* edge_b    = (const float*)d_in[8];
    const float* Wq        = (const float*)d_in[9];
    const float* bq        = (const float*)d_in[10];
    const float* Wk        = (const float*)d_in[11];
    const float* bk        = (const float*)d_in[12];
    const float* Wv        = (const float*)d_in[13];
    const float* bv        = (const float*)d_in[14];
    const float* We        = (const float*)d_in[15];
    const float* be        = (const float*)d_in[16];
    const float* Wskip     = (const float*)d_in[17];
    const float* bskip     = (const float*)d_in[18];
    const float* gamma     = (const float*)d_in[19];
    const float* beta      = (const float*)d_in[20];
    const float* gate_W    = (const float*)d_in[21];
    const float* gate_b    = (const float*)d_in[22];
    const float* out_W     = (const float*)d_in[23];
    const float* out_b     = (const float*)d_in[24];
    float* out = (float*)d_out;

    const int N = in_sizes[0] / 16;
    const int E = in_sizes[2];
    const int B = out_size;

    char* ws = (char*)d_ws;
    size_t off = 0;
    auto alloc = [&](size_t bytes) {
        size_t o = off;
        off += (bytes + 255) & ~(size_t)255;
        return o;
    };
    float*    h      = (float*)(ws + alloc((size_t)N * 64 * 4));
    float*    qkv    = (float*)(ws + alloc((size_t)N * 384 * 4));
    float*    outbuf = (float*)(ws + alloc((size_t)N * 64 * 4));
    int*      rowptr = (int*)(ws + alloc((size_t)(N + 1) * 4));
    int*      cursor = (int*)(ws + alloc((size_t)N * 4));
    int*      counts = (int*)(ws + alloc((size_t)N * 4));
    int*      bsums  = (int*)(ws + alloc(1024));
    int*      csr    = (int*)(ws + alloc((size_t)E * 4));
    float*    Wc     = (float*)(ws + alloc(2 * 1024 * 4));
    float*    bcb    = (float*)(ws + alloc(2 * 128 * 4));
    float*    bnbuf  = (float*)(ws + alloc(256 * 4));
    float*    gate   = (float*)(ws + alloc((size_t)N * 4));
    float*    gd     = (float*)(ws + alloc(64 * 4));
    float*    pooled = (float*)(ws + alloc(64 * 64 * 4));
    if (off > ws_size) return;

    zero_i32_kernel<<<(N + 255) / 256, 256, 0, stream>>>(counts, N);
    node_enc_kernel<<<(N * 64 + 255) / 256, 256, 0, stream>>>(x, node_W, node_b, h, N);
    combine_w_kernel<<<9, 256, 0, stream>>>(edge_W, edge_b, We, be, Wc, bcb);
    csr_count_kernel<<<(E + 255) / 256, 256, 0, stream>>>(edge_dst, counts, E);
    int nb = (N + 255) / 256;
    scan1_kernel<<<nb, 256, 0, stream>>>(counts, rowptr, bsums, N);
    scan2_kernel<<<1, 256, 0, stream>>>(bsums, nb);
    scan3_kernel<<<nb, 256, 0, stream>>>(rowptr, bsums, cursor, N, E);
    csr_fill_kernel<<<(E + 255) / 256, 256, 0, stream>>>(edge_dst, cursor, csr, E);

    for (int l = 0; l < 2; ++l) {
        qkv_kernel<<<dim3((N + 7) / 8, 4), 128, 0, stream>>>(
            h, Wq + l * 8192, bq + l * 128, Wk + l * 8192, bk + l * 128,
            Wv + l * 8192, bv + l * 128, Wskip + l * 4096, bskip + l * 64,
            qkv, outbuf, N);
        attn_kernel<<<(N + 3) / 4, 256, 0, stream>>>(qkv, edge_attr, edge_src, rowptr, csr,
                                                     Wc + l * 1024, bcb + l * 128, outbuf, N);
        zero_bn_kernel<<<1, 128, 0, stream>>>(bnbuf);
        bnstats_kernel<<<256, 256, 0, stream>>>(outbuf, bnbuf, N);
        bnfinal_kernel<<<1, 64, 0, stream>>>(bnbuf, gamma + l * 64, beta + l * 64, N);
        bnapply_kernel<<<(N * 64 + 255) / 256, 256, 0, stream>>>(outbuf, bnbuf, h, N);
    }

    pool_kernel<<<64, 256, 0, stream>>>(h, batch, gate_W, gate_b, gate, pooled, gd, N);
    final_kernel<<<1, 64, 0, stream>>>(pooled, gd, out_W, out_b, out, B);
}

// Round 5
// 664.250 us; speedup vs baseline: 2.7510x; 1.2920x over previous
//
#include <hip/hip_runtime.h>
#include <hip/hip_bf16.h>

typedef unsigned short ushort_t;
typedef __attribute__((ext_vector_type(8))) short short8;
typedef __attribute__((ext_vector_type(4))) float float4v;

__device__ __forceinline__ float bfu(ushort_t u) {
    return __uint_as_float(((unsigned)u) << 16);
}
__device__ __forceinline__ ushort_t f2bf(float f) {
    __hip_bfloat16 h = __float2bfloat16(f);
    return *reinterpret_cast<ushort_t*>(&h);
}

// ---------------- zero-fill helpers ----------------

__global__ void zero_i32_kernel(int* __restrict__ p, int n) {
    int i = blockIdx.x * 256 + threadIdx.x;
    if (i < n) p[i] = 0;
}

__global__ void zero_bn_kernel(float* __restrict__ bnbuf) {
    int t = threadIdx.x;
    if (t < 128) bnbuf[t] = 0.f;
}

// ---------------- encoders & weight prep ----------------

__global__ void node_enc_kernel(const float* __restrict__ x, const float* __restrict__ node_W,
                                const float* __restrict__ node_b, float* __restrict__ h,
                                ushort_t* __restrict__ h_bf, int N) {
    int idx = blockIdx.x * 256 + threadIdx.x;
    if (idx >= N * 64) return;
    int n = idx >> 6, c = idx & 63;
    float acc = node_b[c];
#pragma unroll
    for (int j = 0; j < 16; ++j) acc += x[n * 16 + j] * node_W[j * 64 + c];
    h[idx] = acc;
    h_bf[idx] = f2bf(acc);
}

// Wc[l][d][j] = sum_m edge_W[d][m]*We[l][m][j];  bcb[l][j] = sum_m edge_b[m]*We[l][m][j] + be[l][j]
__global__ void combine_w_kernel(const float* __restrict__ edge_W, const float* __restrict__ edge_b,
                                 const float* __restrict__ We, const float* __restrict__ be,
                                 float* __restrict__ Wc, float* __restrict__ bcb) {
    int tid = blockIdx.x * 256 + threadIdx.x;
    if (tid < 2048) {
        int l = tid >> 10, d = (tid >> 7) & 7, j = tid & 127;
        float s = 0.f;
        for (int m = 0; m < 64; ++m) s += edge_W[d * 64 + m] * We[l * 8192 + m * 128 + j];
        Wc[l * 1024 + d * 128 + j] = s;
    } else if (tid < 2048 + 256) {
        int u = tid - 2048;
        int l = u >> 7, j = u & 127;
        float s = be[l * 128 + j];
        for (int m = 0; m < 64; ++m) s += edge_b[m] * We[l * 8192 + m * 128 + j];
        bcb[l * 128 + j] = s;
    }
}

// Pre-swizzle q|k|v|skip weights into MFMA B-fragment order (bf16) + bias vector.
// Wall_arr[l][ct][kch][lane][j] = W[k= kch*32 + (lane>>4)*8 + j][col= ct*16 + (lane&15)]
__global__ void prep_w_kernel(const float* __restrict__ Wq, const float* __restrict__ Wk,
                              const float* __restrict__ Wv, const float* __restrict__ Wskip,
                              const float* __restrict__ bq, const float* __restrict__ bk,
                              const float* __restrict__ bv, const float* __restrict__ bskip,
                              ushort_t* __restrict__ Wall_arr, float* __restrict__ Wall_bias) {
    int tid = blockIdx.x * 256 + threadIdx.x;
    if (tid < 2 * 28672) {
        int l = tid / 28672, u = tid % 28672;
        int j = u & 7, ln = (u >> 3) & 63, kch = (u >> 9) & 1, ct = u >> 10;
        int nn = ln & 15, quad = ln >> 4;
        int k = kch * 32 + quad * 8 + j;
        int col = ct * 16 + nn;
        float v;
        if (col < 128)      v = Wq[l * 8192 + k * 128 + col];
        else if (col < 256) v = Wk[l * 8192 + k * 128 + col - 128];
        else if (col < 384) v = Wv[l * 8192 + k * 128 + col - 256];
        else                v = Wskip[l * 4096 + k * 64 + col - 384];
        Wall_arr[(size_t)l * 28672 + u] = f2bf(v);
    } else if (tid < 2 * 28672 + 2 * 448) {
        int u = tid - 2 * 28672;
        int l = u / 448, col = u % 448;
        float v;
        if (col < 128)      v = bq[l * 128 + col];
        else if (col < 256) v = bk[l * 128 + col - 128];
        else if (col < 384) v = bv[l * 128 + col - 256];
        else                v = bskip[l * 64 + col - 384];
        Wall_bias[l * 448 + col] = v;
    }
}

// ---------------- CSR build (by dst) ----------------

__global__ void csr_count_kernel(const int* __restrict__ dst, int* __restrict__ counts, int E) {
    int e = blockIdx.x * 256 + threadIdx.x;
    if (e < E) atomicAdd(&counts[dst[e]], 1);
}

__global__ void scan1_kernel(const int* __restrict__ counts, int* __restrict__ rowptr,
                             int* __restrict__ bsums, int N) {
    __shared__ int s[256];
    int t = threadIdx.x, i = blockIdx.x * 256 + t;
    int v = (i < N) ? counts[i] : 0;
    s[t] = v;
    __syncthreads();
    for (int d = 1; d < 256; d <<= 1) {
        int x = (t >= d) ? s[t - d] : 0;
        __syncthreads();
        s[t] += x;
        __syncthreads();
    }
    if (i < N) rowptr[i] = s[t] - v;
    if (t == 255) bsums[blockIdx.x] = s[255];
}

__global__ void scan2_kernel(int* __restrict__ bsums, int nb) {
    __shared__ int s[256];
    int t = threadIdx.x;
    int v = (t < nb) ? bsums[t] : 0;
    s[t] = v;
    __syncthreads();
    for (int d = 1; d < 256; d <<= 1) {
        int x = (t >= d) ? s[t - d] : 0;
        __syncthreads();
        s[t] += x;
        __syncthreads();
    }
    if (t < nb) bsums[t] = s[t] - v;
}

__global__ void scan3_kernel(int* __restrict__ rowptr, const int* __restrict__ bsums,
                             int* __restrict__ cursor, int N, int E) {
    int i = blockIdx.x * 256 + threadIdx.x;
    if (i < N) {
        int r = rowptr[i] + bsums[i >> 8];
        rowptr[i] = r;
        cursor[i] = r;
    }
    if (i == 0) rowptr[N] = E;
}

__global__ void csr_fill_kernel(const int* __restrict__ dst, int* __restrict__ cursor,
                                int* __restrict__ csr, int E) {
    int e = blockIdx.x * 256 + threadIdx.x;
    if (e < E) {
        int pos = atomicAdd(&cursor[dst[e]], 1);
        csr[pos] = e;
    }
}

// ---------------- per-layer kernels ----------------

// MFMA GEMM: [16 nodes x 64] @ [64 x 448] per block (4 waves x 7 col-tiles).
// cols 0..383 -> qkv bf16 [N][384]; cols 384..447 -> outbuf fp32 (skip term).
__global__ __launch_bounds__(256) void qkv_mfma_kernel(
    const ushort_t* __restrict__ h_bf, const ushort_t* __restrict__ Wall_arr,
    const float* __restrict__ Wall_bias,
    ushort_t* __restrict__ qkv, float* __restrict__ outbuf, int N) {
    int wave = threadIdx.x >> 6, lane = threadIdx.x & 63;
    int quad = lane >> 4, nn = lane & 15;
    int n0 = blockIdx.x * 16;
    int node_a = n0 + nn;
    if (node_a >= N) node_a = N - 1;   // A garbage rows masked at store
    const ushort_t* ap = h_bf + (size_t)node_a * 64 + quad * 8;
    short8 a0 = *(const short8*)ap;
    short8 a1 = *(const short8*)(ap + 32);
#pragma unroll
    for (int i = 0; i < 7; ++i) {
        int ct = wave * 7 + i;
        const ushort_t* bp = Wall_arr + ((size_t)(ct * 2) * 64 + lane) * 8;
        short8 b0 = *(const short8*)bp;
        short8 b1 = *(const short8*)(bp + 512);
        float4v c = {0.f, 0.f, 0.f, 0.f};
        c = __builtin_amdgcn_mfma_f32_16x16x32_bf16(a0, b0, c, 0, 0, 0);
        c = __builtin_amdgcn_mfma_f32_16x16x32_bf16(a1, b1, c, 0, 0, 0);
        int col = ct * 16 + nn;
        float bias = Wall_bias[col];
        if (col < 384) {
            ushort_t* qp = qkv + (size_t)(n0 + quad * 4) * 384 + col;
#pragma unroll
            for (int r = 0; r < 4; ++r)
                if (n0 + quad * 4 + r < N) qp[(size_t)r * 384] = f2bf(c[r] + bias);
        } else {
            float* op = outbuf + (size_t)(n0 + quad * 4) * 64 + (col - 384);
#pragma unroll
            for (int r = 0; r < 4; ++r)
                if (n0 + quad * 4 + r < N) op[(size_t)r * 64] = c[r] + bias;
        }
    }
}

// one wave per dst node: online-softmax attention over in-edges; adds onto skip in outbuf
__global__ __launch_bounds__(256) void attn_kernel(
    const ushort_t* __restrict__ qkv,
    const float* __restrict__ edge_attr, const int* __restrict__ edge_src,
    const int* __restrict__ rowptr, const int* __restrict__ csr,
    const float* __restrict__ Wc, const float* __restrict__ bcb,
    float* __restrict__ outbuf, int N) {
    __shared__ float Wc_s[1024];
    __shared__ float bc_s[128];
    int t = threadIdx.x;
    for (int i = t; i < 1024; i += 256) Wc_s[i] = Wc[i];
    if (t < 128) bc_s[t] = bcb[t];
    __syncthreads();
    int lane = t & 63, wid = t >> 6;
    for (int n = blockIdx.x * 4 + wid; n < N; n += gridDim.x * 4) {
        const ushort_t* qp = qkv + (size_t)n * 384;
        float q0 = bfu(qp[lane]), q1 = bfu(qp[64 + lane]);
        int start = rowptr[n], end = rowptr[n + 1];
        float m0 = -1e30f, m1 = -1e30f, l0 = 0.f, l1 = 0.f, a0 = 0.f, a1 = 0.f;
        int e = (start < end) ? csr[start] : 0;
        int src = (start < end) ? edge_src[e] : 0;
        for (int i = start; i < end; ++i) {
            int e_c = e, src_c = src;
            if (i + 1 < end) {
                e = csr[i + 1];
                src = edge_src[e];
            }
            const float4 ea0 = *(const float4*)(edge_attr + (size_t)e_c * 8);
            const float4 ea1 = *(const float4*)(edge_attr + (size_t)e_c * 8 + 4);
            float ep0 = bc_s[lane], ep1 = bc_s[64 + lane];
            ep0 += ea0.x * Wc_s[0 * 128 + lane] + ea0.y * Wc_s[1 * 128 + lane] +
                   ea0.z * Wc_s[2 * 128 + lane] + ea0.w * Wc_s[3 * 128 + lane] +
                   ea1.x * Wc_s[4 * 128 + lane] + ea1.y * Wc_s[5 * 128 + lane] +
                   ea1.z * Wc_s[6 * 128 + lane] + ea1.w * Wc_s[7 * 128 + lane];
            ep1 += ea0.x * Wc_s[0 * 128 + 64 + lane] + ea0.y * Wc_s[1 * 128 + 64 + lane] +
                   ea0.z * Wc_s[2 * 128 + 64 + lane] + ea0.w * Wc_s[3 * 128 + 64 + lane] +
                   ea1.x * Wc_s[4 * 128 + 64 + lane] + ea1.y * Wc_s[5 * 128 + 64 + lane] +
                   ea1.z * Wc_s[6 * 128 + 64 + lane] + ea1.w * Wc_s[7 * 128 + 64 + lane];
            const ushort_t* kp = qkv + (size_t)src_c * 384;
            float ke0 = bfu(kp[128 + lane]) + ep0, ke1 = bfu(kp[192 + lane]) + ep1;
            float ve0 = bfu(kp[256 + lane]) + ep0, ve1 = bfu(kp[320 + lane]) + ep1;
            float s0 = q0 * ke0, s1 = q1 * ke1;
#pragma unroll
            for (int off = 32; off; off >>= 1) {
                s0 += __shfl_xor(s0, off);
                s1 += __shfl_xor(s1, off);
            }
            s0 *= 0.125f;
            s1 *= 0.125f;
            float mn0 = fmaxf(m0, s0);
            float c0 = __expf(m0 - mn0), p0 = __expf(s0 - mn0);
            a0 = a0 * c0 + p0 * ve0;
            l0 = l0 * c0 + p0;
            m0 = mn0;
            float mn1 = fmaxf(m1, s1);
            float c1 = __expf(m1 - mn1), p1 = __expf(s1 - mn1);
            a1 = a1 * c1 + p1 * ve1;
            l1 = l1 * c1 + p1;
            m1 = mn1;
        }
        float attn = (end > start) ? 0.5f * (a0 / l0 + a1 / l1) : 0.f;
        size_t oi = (size_t)n * 64 + lane;
        outbuf[oi] = outbuf[oi] + attn;
    }
}

__global__ __launch_bounds__(256) void bnstats_kernel(const float* __restrict__ outbuf,
                                                      float* __restrict__ bnbuf, int N) {
    __shared__ float ssum[64], ssq[64];
    int t = threadIdx.x;
    if (t < 64) { ssum[t] = 0.f; ssq[t] = 0.f; }
    __syncthreads();
    int stride = gridDim.x * 256;
    float a = 0.f, b = 0.f;
    int idx0 = blockIdx.x * 256 + t;
    for (int idx = idx0; idx < N * 64; idx += stride) {
        float v = outbuf[idx];
        a += v;
        b += v * v;
    }
    int c = t & 63;
    atomicAdd(&ssum[c], a);
    atomicAdd(&ssq[c], b);
    __syncthreads();
    if (t < 64) {
        atomicAdd(&bnbuf[t], ssum[t]);
        atomicAdd(&bnbuf[64 + t], ssq[t]);
    }
}

__global__ void bnfinal_kernel(float* __restrict__ bnbuf, const float* __restrict__ gamma,
                               const float* __restrict__ beta, int N) {
    int c = threadIdx.x;
    if (c >= 64) return;
    float invN = 1.f / (float)N;
    float mean = bnbuf[c] * invN;
    float var = bnbuf[64 + c] * invN - mean * mean;
    float inv = rsqrtf(var + 1e-5f);
    float scale = gamma[c] * inv;
    bnbuf[128 + c] = scale;
    bnbuf[192 + c] = beta[c] - mean * scale;
}

__global__ void bnapply_kernel(const float* __restrict__ outbuf, const float* __restrict__ bnbuf,
                               float* __restrict__ h, ushort_t* __restrict__ h_bf, int N) {
    int idx = blockIdx.x * 256 + threadIdx.x;
    if (idx >= N * 64) return;
    int c = idx & 63;
    float o = outbuf[idx] * bnbuf[128 + c] + bnbuf[192 + c];
    o = (o > 0.f) ? o : 0.01f * o;
    float hn = h[idx] + o;
    h[idx] = hn;
    h_bf[idx] = f2bf(hn);
}

// ---------------- pooling: one block per graph (batch is sorted; no atomics) ----

__global__ __launch_bounds__(256) void pool_kernel(
    const float* __restrict__ h, const int* __restrict__ batch,
    const float* __restrict__ gate_W, const float* __restrict__ gate_b,
    float* __restrict__ gatebuf, float* __restrict__ pooled,
    float* __restrict__ gd, int N) {
    int b = blockIdx.x;
    int lo = 0, hi = N;
    while (lo < hi) { int mid = (lo + hi) >> 1; if (batch[mid] < b) lo = mid + 1; else hi = mid; }
    int start = lo;
    lo = start; hi = N;
    while (lo < hi) { int mid = (lo + hi) >> 1; if (batch[mid] <= b) lo = mid + 1; else hi = mid; }
    int end = lo;
    int lane = threadIdx.x & 63, wid = threadIdx.x >> 6;
    float gw = gate_W[lane];
    float gb = gate_b[0];
    __shared__ float smax[4];
    __shared__ float sacc[4][64];
    __shared__ float sden[4];
    float wmax = -1e30f;
    for (int n = start + wid; n < end; n += 4) {
        float g = h[(size_t)n * 64 + lane] * gw;
#pragma unroll
        for (int off = 32; off; off >>= 1) g += __shfl_xor(g, off);
        g += gb;
        if (lane == 0) gatebuf[n] = g;
        wmax = fmaxf(wmax, g);
    }
    if (lane == 0) smax[wid] = wmax;
    __syncthreads();
    float m = fmaxf(fmaxf(smax[0], smax[1]), fmaxf(smax[2], smax[3]));
    float acc = 0.f, den = 0.f;
    for (int n = start + wid; n < end; n += 4) {
        float ge = __expf(gatebuf[n] - m);
        acc += ge * h[(size_t)n * 64 + lane];
        den += ge;
    }
    sacc[wid][lane] = acc;
    if (lane == 0) sden[wid] = den;
    __syncthreads();
    if (wid == 0) {
        pooled[b * 64 + lane] = sacc[0][lane] + sacc[1][lane] + sacc[2][lane] + sacc[3][lane];
        if (lane == 0) {
            float d = sden[0] + sden[1] + sden[2] + sden[3];
            gd[b] = (end > start) ? d : 1.f;
        }
    }
}

__global__ void final_kernel(const float* __restrict__ pooled, const float* __restrict__ gd,
                             const float* __restrict__ out_W, const float* __restrict__ out_b,
                             float* __restrict__ out, int B) {
    int b = threadIdx.x;
    if (b >= B) return;
    float inv = 1.f / gd[b];
    float s = 0.f;
    for (int c = 0; c < 64; ++c) s += pooled[b * 64 + c] * out_W[c];
    s = s * inv + out_b[0];
    out[b] = 1.f / (1.f + __expf(-s));
}

// ---------------- host ----------------

extern "C" void kernel_launch(void* const* d_in, const int* in_sizes, int n_in,
                              void* d_out, int out_size, void* d_ws, size_t ws_size,
                              hipStream_t stream) {
    const float* x         = (const float*)d_in[0];
    const float* edge_attr = (const float*)d_in[1];
    const int*   edge_src  = (const int*)d_in[2];
    const int*   edge_dst  = (const int*)d_in[3];
    const int*   batch     = (const int*)d_in[4];
    const float* node_W    = (const float*)d_in[5];
    const float* node_b    = (const float*)d_in[6];
    const float* edge_W    = (const float*)d_in[7];
    const float* edge_b    = (const float*)d_in[8];
    const float* Wq        = (const float*)d_in[9];
    const float* bq        = (const float*)d_in[10];
    const float* Wk        = (const float*)d_in[11];
    const float* bk        = (const float*)d_in[12];
    const float* Wv        = (const float*)d_in[13];
    const float* bv        = (const float*)d_in[14];
    const float* We        = (const float*)d_in[15];
    const float* be        = (const float*)d_in[16];
    const float* Wskip     = (const float*)d_in[17];
    const float* bskip     = (const float*)d_in[18];
    const float* gamma     = (const float*)d_in[19];
    const float* beta      = (const float*)d_in[20];
    const float* gate_W    = (const float*)d_in[21];
    const float* gate_b    = (const float*)d_in[22];
    const float* out_W     = (const float*)d_in[23];
    const float* out_b     = (const float*)d_in[24];
    float* out = (float*)d_out;

    const int N = in_sizes[0] / 16;
    const int E = in_sizes[2];
    const int B = out_size;

    char* ws = (char*)d_ws;
    size_t off = 0;
    auto alloc = [&](size_t bytes) {
        size_t o = off;
        off += (bytes + 255) & ~(size_t)255;
        return o;
    };
    float*    h        = (float*)(ws + alloc((size_t)N * 64 * 4));
    ushort_t* h_bf     = (ushort_t*)(ws + alloc((size_t)N * 64 * 2));
    ushort_t* qkv      = (ushort_t*)(ws + alloc((size_t)N * 384 * 2));
    float*    outbuf   = (float*)(ws + alloc((size_t)N * 64 * 4));
    int*      rowptr   = (int*)(ws + alloc((size_t)(N + 1) * 4));
    int*      cursor   = (int*)(ws + alloc((size_t)N * 4));
    int*      counts   = (int*)(ws + alloc((size_t)N * 4));
    int*      bsums    = (int*)(ws + alloc(1024));
    int*      csr      = (int*)(ws + alloc((size_t)E * 4));
    float*    Wc       = (float*)(ws + alloc(2 * 1024 * 4));
    float*    bcb      = (float*)(ws + alloc(2 * 128 * 4));
    ushort_t* Wall_arr = (ushort_t*)(ws + alloc(2 * 28672 * 2));
    float*    Wall_b   = (float*)(ws + alloc(2 * 448 * 4));
    float*    bnbuf    = (float*)(ws + alloc(256 * 4));
    float*    gate     = (float*)(ws + alloc((size_t)N * 4));
    float*    gd       = (float*)(ws + alloc(64 * 4));
    float*    pooled   = (float*)(ws + alloc(64 * 64 * 4));
    if (off > ws_size) return;

    zero_i32_kernel<<<(N + 255) / 256, 256, 0, stream>>>(counts, N);
    node_enc_kernel<<<(N * 64 + 255) / 256, 256, 0, stream>>>(x, node_W, node_b, h, h_bf, N);
    combine_w_kernel<<<9, 256, 0, stream>>>(edge_W, edge_b, We, be, Wc, bcb);
    prep_w_kernel<<<(2 * 28672 + 2 * 448 + 255) / 256, 256, 0, stream>>>(
        Wq, Wk, Wv, Wskip, bq, bk, bv, bskip, Wall_arr, Wall_b);
    csr_count_kernel<<<(E + 255) / 256, 256, 0, stream>>>(edge_dst, counts, E);
    int nb = (N + 255) / 256;
    scan1_kernel<<<nb, 256, 0, stream>>>(counts, rowptr, bsums, N);
    scan2_kernel<<<1, 256, 0, stream>>>(bsums, nb);
    scan3_kernel<<<nb, 256, 0, stream>>>(rowptr, bsums, cursor, N, E);
    csr_fill_kernel<<<(E + 255) / 256, 256, 0, stream>>>(edge_dst, cursor, csr, E);

    for (int l = 0; l < 2; ++l) {
        qkv_mfma_kernel<<<(N + 15) / 16, 256, 0, stream>>>(
            h_bf, Wall_arr + (size_t)l * 28672, Wall_b + l * 448, qkv, outbuf, N);
        attn_kernel<<<(N + 3) / 4, 256, 0, stream>>>(qkv, edge_attr, edge_src, rowptr, csr,
                                                     Wc + l * 1024, bcb + l * 128, outbuf, N);
        zero_bn_kernel<<<1, 128, 0, stream>>>(bnbuf);
        bnstats_kernel<<<256, 256, 0, stream>>>(outbuf, bnbuf, N);
        bnfinal_kernel<<<1, 64, 0, stream>>>(bnbuf, gamma + l * 64, beta + l * 64, N);
        bnapply_kernel<<<(N * 64 + 255) / 256, 256, 0, stream>>>(outbuf, bnbuf, h, h_bf, N);
    }

    pool_kernel<<<64, 256, 0, stream>>>(h, batch, gate_W, gate_b, gate, pooled, gd, N);
    final_kernel<<<1, 64, 0, stream>>>(pooled, gd, out_W, out_b, out, B);
}

// Round 6
// 624.031 us; speedup vs baseline: 2.9283x; 1.0645x over previous
//
#include <hip/hip_runtime.h>
#include <hip/hip_bf16.h>

typedef unsigned short ushort_t;
typedef __attribute__((ext_vector_type(8))) short short8;
typedef __attribute__((ext_vector_type(4))) float float4v;

__device__ __forceinline__ float bfu(ushort_t u) {
    return __uint_as_float(((unsigned)u) << 16);
}
__device__ __forceinline__ ushort_t f2bf(float f) {
    __hip_bfloat16 h = __float2bfloat16(f);
    return *reinterpret_cast<ushort_t*>(&h);
}

// ---------------- zero-fill helpers ----------------

__global__ void zero_i32_kernel(int* __restrict__ p, int n) {
    int i = blockIdx.x * 256 + threadIdx.x;
    if (i < n) p[i] = 0;
}

__global__ void zero_bn_kernel(float* __restrict__ bnbuf) {
    int t = threadIdx.x;
    if (t < 128) bnbuf[t] = 0.f;
}

// ---------------- encoders & weight prep ----------------

__global__ void node_enc_kernel(const float* __restrict__ x, const float* __restrict__ node_W,
                                const float* __restrict__ node_b, float* __restrict__ h,
                                ushort_t* __restrict__ h_bf, int N) {
    int idx = blockIdx.x * 256 + threadIdx.x;
    if (idx >= N * 64) return;
    int n = idx >> 6, c = idx & 63;
    float acc = node_b[c];
#pragma unroll
    for (int j = 0; j < 16; ++j) acc += x[n * 16 + j] * node_W[j * 64 + c];
    h[idx] = acc;
    h_bf[idx] = f2bf(acc);
}

// Wc[l][d][j] = sum_m edge_W[d][m]*We[l][m][j];  bcb[l][j] = sum_m edge_b[m]*We[l][m][j] + be[l][j]
__global__ void combine_w_kernel(const float* __restrict__ edge_W, const float* __restrict__ edge_b,
                                 const float* __restrict__ We, const float* __restrict__ be,
                                 float* __restrict__ Wc, float* __restrict__ bcb) {
    int tid = blockIdx.x * 256 + threadIdx.x;
    if (tid < 2048) {
        int l = tid >> 10, d = (tid >> 7) & 7, j = tid & 127;
        float s = 0.f;
        for (int m = 0; m < 64; ++m) s += edge_W[d * 64 + m] * We[l * 8192 + m * 128 + j];
        Wc[l * 1024 + d * 128 + j] = s;
    } else if (tid < 2048 + 256) {
        int u = tid - 2048;
        int l = u >> 7, j = u & 127;
        float s = be[l * 128 + j];
        for (int m = 0; m < 64; ++m) s += edge_b[m] * We[l * 8192 + m * 128 + j];
        bcb[l * 128 + j] = s;
    }
}

// Wqc_all[l][k][j] (j<16: 0.125*Wq[k][h*64+:]·Wc[d][h*64+:], h=j>>3,d=j&7;
//                  j=16,17: 0.125*Wq[k][h*64+:]·bcb[h*64+:], h=j-16)
// bias18[l][j]: same with bq in place of Wq[k].
__global__ void combine2_kernel(const float* __restrict__ Wq, const float* __restrict__ bq,
                                const float* __restrict__ Wc, const float* __restrict__ bcb,
                                float* __restrict__ Wqc_all, float* __restrict__ bias18) {
    int tid = blockIdx.x * 256 + threadIdx.x;
    if (tid < 2304) {
        int l = tid / 1152, u = tid % 1152, k = u / 18, j = u % 18;
        float s = 0.f;
        if (j < 16) {
            int hh = j >> 3, d = j & 7;
            for (int c = 0; c < 64; ++c)
                s += Wq[l * 8192 + k * 128 + hh * 64 + c] * Wc[l * 1024 + d * 128 + hh * 64 + c];
        } else {
            int hh = j - 16;
            for (int c = 0; c < 64; ++c)
                s += Wq[l * 8192 + k * 128 + hh * 64 + c] * bcb[l * 128 + hh * 64 + c];
        }
        Wqc_all[l * 1152 + k * 18 + j] = 0.125f * s;
    } else if (tid < 2304 + 36) {
        int u = tid - 2304;
        int l = u / 18, j = u % 18;
        float s = 0.f;
        if (j < 16) {
            int hh = j >> 3, d = j & 7;
            for (int c = 0; c < 64; ++c)
                s += bq[l * 128 + hh * 64 + c] * Wc[l * 1024 + d * 128 + hh * 64 + c];
        } else {
            int hh = j - 16;
            for (int c = 0; c < 64; ++c)
                s += bq[l * 128 + hh * 64 + c] * bcb[l * 128 + hh * 64 + c];
        }
        bias18[l * 18 + j] = 0.125f * s;
    }
}

// Pre-swizzle q|k|v|skip weights into MFMA B-fragment order (bf16) + bias vector.
__global__ void prep_w_kernel(const float* __restrict__ Wq, const float* __restrict__ Wk,
                              const float* __restrict__ Wv, const float* __restrict__ Wskip,
                              const float* __restrict__ bq, const float* __restrict__ bk,
                              const float* __restrict__ bv, const float* __restrict__ bskip,
                              ushort_t* __restrict__ Wall_arr, float* __restrict__ Wall_bias) {
    int tid = blockIdx.x * 256 + threadIdx.x;
    if (tid < 2 * 28672) {
        int l = tid / 28672, u = tid % 28672;
        int j = u & 7, ln = (u >> 3) & 63, kch = (u >> 9) & 1, ct = u >> 10;
        int nn = ln & 15, quad = ln >> 4;
        int k = kch * 32 + quad * 8 + j;
        int col = ct * 16 + nn;
        float v;
        if (col < 128)      v = Wq[l * 8192 + k * 128 + col];
        else if (col < 256) v = Wk[l * 8192 + k * 128 + col - 128];
        else if (col < 384) v = Wv[l * 8192 + k * 128 + col - 256];
        else                v = Wskip[l * 4096 + k * 64 + col - 384];
        Wall_arr[(size_t)l * 28672 + u] = f2bf(v);
    } else if (tid < 2 * 28672 + 2 * 448) {
        int u = tid - 2 * 28672;
        int l = u / 448, col = u % 448;
        float v;
        if (col < 128)      v = bq[l * 128 + col];
        else if (col < 256) v = bk[l * 128 + col - 128];
        else if (col < 384) v = bv[l * 128 + col - 256];
        else                v = bskip[l * 64 + col - 384];
        Wall_bias[l * 448 + col] = v;
    }
}

// ---------------- CSR build (by dst) ----------------

__global__ void csr_count_kernel(const int* __restrict__ dst, int* __restrict__ counts, int E) {
    int e = blockIdx.x * 256 + threadIdx.x;
    if (e < E) atomicAdd(&counts[dst[e]], 1);
}

__global__ void scan1_kernel(const int* __restrict__ counts, int* __restrict__ rowptr,
                             int* __restrict__ bsums, int N) {
    __shared__ int s[256];
    int t = threadIdx.x, i = blockIdx.x * 256 + t;
    int v = (i < N) ? counts[i] : 0;
    s[t] = v;
    __syncthreads();
    for (int d = 1; d < 256; d <<= 1) {
        int x = (t >= d) ? s[t - d] : 0;
        __syncthreads();
        s[t] += x;
        __syncthreads();
    }
    if (i < N) rowptr[i] = s[t] - v;
    if (t == 255) bsums[blockIdx.x] = s[255];
}

__global__ void scan2_kernel(int* __restrict__ bsums, int nb) {
    __shared__ int s[256];
    int t = threadIdx.x;
    int v = (t < nb) ? bsums[t] : 0;
    s[t] = v;
    __syncthreads();
    for (int d = 1; d < 256; d <<= 1) {
        int x = (t >= d) ? s[t - d] : 0;
        __syncthreads();
        s[t] += x;
        __syncthreads();
    }
    if (t < nb) bsums[t] = s[t] - v;
}

__global__ void scan3_kernel(int* __restrict__ rowptr, const int* __restrict__ bsums,
                             int* __restrict__ cursor, int N, int E) {
    int i = blockIdx.x * 256 + threadIdx.x;
    if (i < N) {
        int r = rowptr[i] + bsums[i >> 8];
        rowptr[i] = r;
        cursor[i] = r;
    }
    if (i == 0) rowptr[N] = E;
}

__global__ void csr_fill_kernel(const int* __restrict__ dst, int* __restrict__ cursor,
                                int* __restrict__ csr, int E) {
    int e = blockIdx.x * 256 + threadIdx.x;
    if (e < E) {
        int pos = atomicAdd(&cursor[dst[e]], 1);
        csr[pos] = e;
    }
}

// ---------------- per-layer kernels ----------------

// MFMA GEMM: [16 nodes x 64] @ [64 x 448]; cols 0..383 -> qkv bf16; 384..447 -> outbuf (skip)
__global__ __launch_bounds__(256) void qkv_mfma_kernel(
    const ushort_t* __restrict__ h_bf, const ushort_t* __restrict__ Wall_arr,
    const float* __restrict__ Wall_bias,
    ushort_t* __restrict__ qkv, float* __restrict__ outbuf, int N) {
    int wave = threadIdx.x >> 6, lane = threadIdx.x & 63;
    int quad = lane >> 4, nn = lane & 15;
    int n0 = blockIdx.x * 16;
    int node_a = n0 + nn;
    if (node_a >= N) node_a = N - 1;
    const ushort_t* ap = h_bf + (size_t)node_a * 64 + quad * 8;
    short8 a0 = *(const short8*)ap;
    short8 a1 = *(const short8*)(ap + 32);
#pragma unroll
    for (int i = 0; i < 7; ++i) {
        int ct = wave * 7 + i;
        const ushort_t* bp = Wall_arr + ((size_t)(ct * 2) * 64 + lane) * 8;
        short8 b0 = *(const short8*)bp;
        short8 b1 = *(const short8*)(bp + 512);
        float4v c = {0.f, 0.f, 0.f, 0.f};
        c = __builtin_amdgcn_mfma_f32_16x16x32_bf16(a0, b0, c, 0, 0, 0);
        c = __builtin_amdgcn_mfma_f32_16x16x32_bf16(a1, b1, c, 0, 0, 0);
        int col = ct * 16 + nn;
        float bias = Wall_bias[col];
        if (col < 384) {
            ushort_t* qp = qkv + (size_t)(n0 + quad * 4) * 384 + col;
#pragma unroll
            for (int r = 0; r < 4; ++r)
                if (n0 + quad * 4 + r < N) qp[(size_t)r * 384] = f2bf(c[r] + bias);
        } else {
            float* op = outbuf + (size_t)(n0 + quad * 4) * 64 + (col - 384);
#pragma unroll
            for (int r = 0; r < 4; ++r)
                if (n0 + quad * 4 + r < N) op[(size_t)r * 64] = c[r] + bias;
        }
    }
}

// qcbuf[n][20]: j<16: qc (0.125*(Wc q)); j=16,17: 0.125*q·bcb per head; fp32 for precision
__global__ __launch_bounds__(256) void qc_kernel(const float* __restrict__ h,
                                                 const float* __restrict__ Wqc,
                                                 const float* __restrict__ bias18,
                                                 float* __restrict__ qcbuf, int N) {
    __shared__ float hs[16 * 64];
    __shared__ float w_s[64 * 18];
    __shared__ float b_s[18];
    int t = threadIdx.x;
    int n0 = blockIdx.x * 16;
    for (int i = t; i < 1152; i += 256) w_s[i] = Wqc[i];
    if (t < 18) b_s[t] = bias18[t];
    for (int i = t; i < 1024; i += 256) {
        int n = n0 + (i >> 6);
        hs[i] = (n < N) ? h[(size_t)n * 64 + (i & 63)] : 0.f;
    }
    __syncthreads();
    for (int o = t; o < 16 * 18; o += 256) {
        int nl = o / 18, j = o % 18;
        int n = n0 + nl;
        if (n < N) {
            float s = b_s[j];
            for (int k = 0; k < 64; ++k) s += hs[nl * 64 + k] * w_s[k * 18 + j];
            qcbuf[(size_t)n * 20 + j] = s;
        }
    }
}

// one wave per dst node; head-split lanes (0-31: head0, 32-63: head1), 2 channels/lane.
// logit = 0.125*q·k[src] + qc·ea + qbc ; p = exp(logit) (no max-sub; clamped at -60)
__global__ __launch_bounds__(256) void attn_kernel(
    const ushort_t* __restrict__ qkv, const float* __restrict__ qcbuf,
    const float* __restrict__ edge_attr, const int* __restrict__ edge_src,
    const int* __restrict__ rowptr, const int* __restrict__ csr,
    const float* __restrict__ Wc, const float* __restrict__ bcb,
    float* __restrict__ outbuf, int N) {
    __shared__ float Wc_s[1024];
    __shared__ float bc_s[128];
    int t = threadIdx.x;
    for (int i = t; i < 1024; i += 256) Wc_s[i] = Wc[i];
    if (t < 128) bc_s[t] = bcb[t];
    __syncthreads();
    int lane = t & 63, wid = t >> 6;
    int half = lane >> 5, l31 = lane & 31;
    for (int n = blockIdx.x * 4 + wid; n < N; n += gridDim.x * 4) {
        const ushort_t* rowq = qkv + (size_t)n * 384;
        unsigned qraw = *(const unsigned*)(rowq + 2 * lane);
        float qx = bfu((ushort_t)(qraw & 0xffff)), qy = bfu((ushort_t)(qraw >> 16));
        const float4 qcA = *(const float4*)(qcbuf + (size_t)n * 20 + half * 8);
        const float4 qcB = *(const float4*)(qcbuf + (size_t)n * 20 + half * 8 + 4);
        float qb = qcbuf[(size_t)n * 20 + 16 + half];
        int start = rowptr[n], end = rowptr[n + 1];
        float lsum = 0.f, ax = 0.f, ay = 0.f;
        float4 se0 = {0.f, 0.f, 0.f, 0.f}, se1 = {0.f, 0.f, 0.f, 0.f};
        int e = 0, src = 0;
        unsigned kraw = 0, vraw = 0;
        float4 ea0 = {0.f, 0.f, 0.f, 0.f}, ea1 = {0.f, 0.f, 0.f, 0.f};
        if (start < end) {
            e = csr[start];
            src = edge_src[e];
            const ushort_t* kp = qkv + (size_t)src * 384;
            kraw = *(const unsigned*)(kp + 128 + 2 * lane);
            vraw = *(const unsigned*)(kp + 256 + 2 * lane);
            ea0 = *(const float4*)(edge_attr + (size_t)e * 8);
            ea1 = *(const float4*)(edge_attr + (size_t)e * 8 + 4);
        }
        for (int i = start; i < end; ++i) {
            unsigned kc = kraw, vc = vraw;
            float4 a0v = ea0, a1v = ea1;
            if (i + 1 < end) {
                int e2 = csr[i + 1];
                int s2 = edge_src[e2];
                const ushort_t* kp2 = qkv + (size_t)s2 * 384;
                kraw = *(const unsigned*)(kp2 + 128 + 2 * lane);
                vraw = *(const unsigned*)(kp2 + 256 + 2 * lane);
                ea0 = *(const float4*)(edge_attr + (size_t)e2 * 8);
                ea1 = *(const float4*)(edge_attr + (size_t)e2 * 8 + 4);
            }
            float kx = bfu((ushort_t)(kc & 0xffff)), ky = bfu((ushort_t)(kc >> 16));
            float s = qx * kx + qy * ky;
            s += __shfl_xor(s, 1);
            s += __shfl_xor(s, 2);
            s += __shfl_xor(s, 4);
            s += __shfl_xor(s, 8);
            s += __shfl_xor(s, 16);
            s = s * 0.125f
              + qcA.x * a0v.x + qcA.y * a0v.y + qcA.z * a0v.z + qcA.w * a0v.w
              + qcB.x * a1v.x + qcB.y * a1v.y + qcB.z * a1v.z + qcB.w * a1v.w + qb;
            float p = __expf(fmaxf(s, -60.f));
            lsum += p;
            float vx = bfu((ushort_t)(vc & 0xffff)), vy = bfu((ushort_t)(vc >> 16));
            ax += p * vx;
            ay += p * vy;
            se0.x += p * a0v.x; se0.y += p * a0v.y; se0.z += p * a0v.z; se0.w += p * a0v.w;
            se1.x += p * a1v.x; se1.y += p * a1v.y; se1.z += p * a1v.z; se1.w += p * a1v.w;
        }
        if (end > start) {
            int j0 = half * 64 + 2 * l31;
            float w0 = lsum * bc_s[j0], w1 = lsum * bc_s[j0 + 1];
            w0 += se0.x * Wc_s[0 * 128 + j0] + se0.y * Wc_s[1 * 128 + j0] +
                  se0.z * Wc_s[2 * 128 + j0] + se0.w * Wc_s[3 * 128 + j0] +
                  se1.x * Wc_s[4 * 128 + j0] + se1.y * Wc_s[5 * 128 + j0] +
                  se1.z * Wc_s[6 * 128 + j0] + se1.w * Wc_s[7 * 128 + j0];
            w1 += se0.x * Wc_s[0 * 128 + j0 + 1] + se0.y * Wc_s[1 * 128 + j0 + 1] +
                  se0.z * Wc_s[2 * 128 + j0 + 1] + se0.w * Wc_s[3 * 128 + j0 + 1] +
                  se1.x * Wc_s[4 * 128 + j0 + 1] + se1.y * Wc_s[5 * 128 + j0 + 1] +
                  se1.z * Wc_s[6 * 128 + j0 + 1] + se1.w * Wc_s[7 * 128 + j0 + 1];
            float inv = 1.f / lsum;
            float ox = (ax + w0) * inv, oy = (ay + w1) * inv;
            float px = __shfl_xor(ox, 32), py = __shfl_xor(oy, 32);
            ox = 0.5f * (ox + px);
            oy = 0.5f * (oy + py);
            if (half == 0) {
                float2* op = (float2*)(outbuf + (size_t)n * 64 + 2 * l31);
                float2 cur = *op;
                *op = make_float2(cur.x + ox, cur.y + oy);
            }
        }
    }
}

__global__ __launch_bounds__(256) void bnstats_kernel(const float* __restrict__ outbuf,
                                                      float* __restrict__ bnbuf, int N) {
    __shared__ float ssum[64], ssq[64];
    int t = threadIdx.x;
    if (t < 64) { ssum[t] = 0.f; ssq[t] = 0.f; }
    __syncthreads();
    int stride = gridDim.x * 256;
    float a = 0.f, b = 0.f;
    int idx0 = blockIdx.x * 256 + t;
    for (int idx = idx0; idx < N * 64; idx += stride) {
        float v = outbuf[idx];
        a += v;
        b += v * v;
    }
    int c = t & 63;
    atomicAdd(&ssum[c], a);
    atomicAdd(&ssq[c], b);
    __syncthreads();
    if (t < 64) {
        atomicAdd(&bnbuf[t], ssum[t]);
        atomicAdd(&bnbuf[64 + t], ssq[t]);
    }
}

__global__ void bnfinal_kernel(float* __restrict__ bnbuf, const float* __restrict__ gamma,
                               const float* __restrict__ beta, int N) {
    int c = threadIdx.x;
    if (c >= 64) return;
    float invN = 1.f / (float)N;
    float mean = bnbuf[c] * invN;
    float var = bnbuf[64 + c] * invN - mean * mean;
    float inv = rsqrtf(var + 1e-5f);
    float scale = gamma[c] * inv;
    bnbuf[128 + c] = scale;
    bnbuf[192 + c] = beta[c] - mean * scale;
}

// BN apply + leaky + residual; also computes gate[n] = h_new·gate_W + gate_b (wave==node)
__global__ __launch_bounds__(256) void bnapply_kernel(
    const float* __restrict__ outbuf, const float* __restrict__ bnbuf,
    const float* __restrict__ gate_W, const float* __restrict__ gate_b,
    float* __restrict__ h, ushort_t* __restrict__ h_bf,
    float* __restrict__ gatebuf, int N) {
    int idx = blockIdx.x * 256 + threadIdx.x;
    if (idx >= N * 64) return;
    int c = idx & 63, n = idx >> 6;
    float o = outbuf[idx] * bnbuf[128 + c] + bnbuf[192 + c];
    o = (o > 0.f) ? o : 0.01f * o;
    float hn = h[idx] + o;
    h[idx] = hn;
    h_bf[idx] = f2bf(hn);
    float g = hn * gate_W[c];
#pragma unroll
    for (int off = 32; off; off >>= 1) g += __shfl_xor(g, off);
    if (c == 0) gatebuf[n] = g + gate_b[0];
}

// ---------------- pooling: gate max -> chunked accumulate -> combine+sigmoid ----

__global__ __launch_bounds__(256) void pool_max_kernel(const float* __restrict__ gatebuf,
                                                       const int* __restrict__ batch,
                                                       float* __restrict__ m, int N) {
    int b = blockIdx.x;
    int lo = 0, hi = N;
    while (lo < hi) { int mid = (lo + hi) >> 1; if (batch[mid] < b) lo = mid + 1; else hi = mid; }
    int start = lo;
    lo = start; hi = N;
    while (lo < hi) { int mid = (lo + hi) >> 1; if (batch[mid] <= b) lo = mid + 1; else hi = mid; }
    int end = lo;
    int t = threadIdx.x, lane = t & 63, wid = t >> 6;
    __shared__ float sm[4];
    float mx = -1e30f;
    for (int n = start + t; n < end; n += 256) mx = fmaxf(mx, gatebuf[n]);
#pragma unroll
    for (int off = 32; off; off >>= 1) mx = fmaxf(mx, __shfl_xor(mx, off));
    if (lane == 0) sm[wid] = mx;
    __syncthreads();
    if (t == 0) m[b] = fmaxf(fmaxf(sm[0], sm[1]), fmaxf(sm[2], sm[3]));
}

__global__ __launch_bounds__(256) void pool_acc_kernel(
    const float* __restrict__ h, const float* __restrict__ gatebuf,
    const int* __restrict__ batch, const float* __restrict__ m,
    float* __restrict__ pacc, float* __restrict__ pden, int N) {
    int b = blockIdx.x >> 3, chunk = blockIdx.x & 7;
    int lo = 0, hi = N;
    while (lo < hi) { int mid = (lo + hi) >> 1; if (batch[mid] < b) lo = mid + 1; else hi = mid; }
    int start = lo;
    lo = start; hi = N;
    while (lo < hi) { int mid = (lo + hi) >> 1; if (batch[mid] <= b) lo = mid + 1; else hi = mid; }
    int end = lo;
    int lane = threadIdx.x & 63, wid = threadIdx.x >> 6;
    int gwid = chunk * 4 + wid;
    float mb = m[b];
    float acc = 0.f, den = 0.f;
    for (int n = start + gwid; n < end; n += 32) {
        float ge = __expf(gatebuf[n] - mb);
        acc += ge * h[(size_t)n * 64 + lane];
        den += ge;
    }
    __shared__ float sacc[4][64];
    __shared__ float sden[4];
    sacc[wid][lane] = acc;
    if (lane == 0) sden[wid] = den;
    __syncthreads();
    if (wid == 0) {
        pacc[(size_t)blockIdx.x * 64 + lane] =
            sacc[0][lane] + sacc[1][lane] + sacc[2][lane] + sacc[3][lane];
        if (lane == 0) pden[blockIdx.x] = sden[0] + sden[1] + sden[2] + sden[3];
    }
}

__global__ void pool_fin_kernel(const float* __restrict__ pacc, const float* __restrict__ pden,
                                const float* __restrict__ out_W, const float* __restrict__ out_b,
                                float* __restrict__ out) {
    int b = blockIdx.x, c = threadIdx.x;
    float pc = 0.f, dv = 0.f;
#pragma unroll
    for (int j = 0; j < 8; ++j) {
        pc += pacc[(size_t)(b * 8 + j) * 64 + c];
        dv += pden[b * 8 + j];
    }
    float s = pc * out_W[c];
#pragma unroll
    for (int off = 32; off; off >>= 1) s += __shfl_xor(s, off);
    if (c == 0) {
        if (dv <= 0.f) dv = 1.f;
        float v = s / dv + out_b[0];
        out[b] = 1.f / (1.f + __expf(-v));
    }
}

// ---------------- host ----------------

extern "C" void kernel_launch(void* const* d_in, const int* in_sizes, int n_in,
                              void* d_out, int out_size, void* d_ws, size_t ws_size,
                              hipStream_t stream) {
    const float* x         = (const float*)d_in[0];
    const float* edge_attr = (const float*)d_in[1];
    const int*   edge_src  = (const int*)d_in[2];
    const int*   edge_dst  = (const int*)d_in[3];
    const int*   batch     = (const int*)d_in[4];
    const float* node_W    = (const float*)d_in[5];
    const float* node_b    = (const float*)d_in[6];
    const float* edge_W    = (const float*)d_in[7];
    const float* edge_b    = (const float*)d_in[8];
    const float* Wq        = (const float*)d_in[9];
    const float* bq        = (const float*)d_in[10];
    const float* Wk        = (const float*)d_in[11];
    const float* bk        = (const float*)d_in[12];
    const float* Wv        = (const float*)d_in[13];
    const float* bv        = (const float*)d_in[14];
    const float* We        = (const float*)d_in[15];
    const float* be        = (const float*)d_in[16];
    const float* Wskip     = (const float*)d_in[17];
    const float* bskip     = (const float*)d_in[18];
    const float* gamma     = (const float*)d_in[19];
    const float* beta      = (const float*)d_in[20];
    const float* gate_W    = (const float*)d_in[21];
    const float* gate_b    = (const float*)d_in[22];
    const float* out_W     = (const float*)d_in[23];
    const float* out_b     = (const float*)d_in[24];
    float* out = (float*)d_out;

    const int N = in_sizes[0] / 16;
    const int E = in_sizes[2];

    char* ws = (char*)d_ws;
    size_t off = 0;
    auto alloc = [&](size_t bytes) {
        size_t o = off;
        off += (bytes + 255) & ~(size_t)255;
        return o;
    };
    float*    h        = (float*)(ws + alloc((size_t)N * 64 * 4));
    ushort_t* h_bf     = (ushort_t*)(ws + alloc((size_t)N * 64 * 2));
    ushort_t* qkv      = (ushort_t*)(ws + alloc((size_t)N * 384 * 2));
    float*    outbuf   = (float*)(ws + alloc((size_t)N * 64 * 4));
    float*    qcbuf    = (float*)(ws + alloc((size_t)N * 20 * 4));
    int*      rowptr   = (int*)(ws + alloc((size_t)(N + 1) * 4));
    int*      cursor   = (int*)(ws + alloc((size_t)N * 4));
    int*      counts   = (int*)(ws + alloc((size_t)N * 4));
    int*      bsums    = (int*)(ws + alloc(1024));
    int*      csr      = (int*)(ws + alloc((size_t)E * 4));
    float*    Wc       = (float*)(ws + alloc(2 * 1024 * 4));
    float*    bcb      = (float*)(ws + alloc(2 * 128 * 4));
    float*    Wqc      = (float*)(ws + alloc(2 * 1152 * 4));
    float*    bias18   = (float*)(ws + alloc(2 * 18 * 4));
    ushort_t* Wall_arr = (ushort_t*)(ws + alloc(2 * 28672 * 2));
    float*    Wall_b   = (float*)(ws + alloc(2 * 448 * 4));
    float*    bnbuf    = (float*)(ws + alloc(256 * 4));
    float*    gatebuf  = (float*)(ws + alloc((size_t)N * 4));
    float*    gmax     = (float*)(ws + alloc(64 * 4));
    float*    pacc     = (float*)(ws + alloc(512 * 64 * 4));
    float*    pden     = (float*)(ws + alloc(512 * 4));
    if (off > ws_size) return;

    zero_i32_kernel<<<(N + 255) / 256, 256, 0, stream>>>(counts, N);
    node_enc_kernel<<<(N * 64 + 255) / 256, 256, 0, stream>>>(x, node_W, node_b, h, h_bf, N);
    combine_w_kernel<<<9, 256, 0, stream>>>(edge_W, edge_b, We, be, Wc, bcb);
    combine2_kernel<<<10, 256, 0, stream>>>(Wq, bq, Wc, bcb, Wqc, bias18);
    prep_w_kernel<<<(2 * 28672 + 2 * 448 + 255) / 256, 256, 0, stream>>>(
        Wq, Wk, Wv, Wskip, bq, bk, bv, bskip, Wall_arr, Wall_b);
    csr_count_kernel<<<(E + 255) / 256, 256, 0, stream>>>(edge_dst, counts, E);
    int nb = (N + 255) / 256;
    scan1_kernel<<<nb, 256, 0, stream>>>(counts, rowptr, bsums, N);
    scan2_kernel<<<1, 256, 0, stream>>>(bsums, nb);
    scan3_kernel<<<nb, 256, 0, stream>>>(rowptr, bsums, cursor, N, E);
    csr_fill_kernel<<<(E + 255) / 256, 256, 0, stream>>>(edge_dst, cursor, csr, E);

    for (int l = 0; l < 2; ++l) {
        qkv_mfma_kernel<<<(N + 15) / 16, 256, 0, stream>>>(
            h_bf, Wall_arr + (size_t)l * 28672, Wall_b + l * 448, qkv, outbuf, N);
        qc_kernel<<<(N + 15) / 16, 256, 0, stream>>>(h, Wqc + l * 1152, bias18 + l * 18,
                                                     qcbuf, N);
        attn_kernel<<<(N + 3) / 4, 256, 0, stream>>>(qkv, qcbuf, edge_attr, edge_src,
                                                     rowptr, csr, Wc + l * 1024,
                                                     bcb + l * 128, outbuf, N);
        zero_bn_kernel<<<1, 128, 0, stream>>>(bnbuf);
        bnstats_kernel<<<256, 256, 0, stream>>>(outbuf, bnbuf, N);
        bnfinal_kernel<<<1, 64, 0, stream>>>(bnbuf, gamma + l * 64, beta + l * 64, N);
        bnapply_kernel<<<(N * 64 + 255) / 256, 256, 0, stream>>>(
            outbuf, bnbuf, gate_W, gate_b, h, h_bf, gatebuf, N);
    }

    pool_max_kernel<<<64, 256, 0, stream>>>(gatebuf, batch, gmax, N);
    pool_acc_kernel<<<512, 256, 0, stream>>>(h, gatebuf, batch, gmax, pacc, pden, N);
    pool_fin_kernel<<<64, 64, 0, stream>>>(pacc, pden, out_W, out_b, out);
}